// Round 3
// baseline (523.160 us; speedup 1.0000x reference)
//
#include <hip/hip_runtime.h>
#include <math.h>

#define BB 8
#define TT 288
#define NN 2000
#define FLEN 145
#define EE 128
#define IDD 16
#define HH 128
#define DKK 144
#define KTOP 20

typedef _Float16 half8 __attribute__((ext_vector_type(8)));
typedef float f32x4 __attribute__((ext_vector_type(4)));
typedef unsigned short ushort_t;

// ---- workspace layout (float offsets) ----
#define OFF_TW  ((size_t)0)
#define SZ_TW   ((size_t)TT*FLEN*2)
#define OFF_XF  (OFF_TW + SZ_TW)
#define SZ_XF   ((size_t)BB*FLEN*NN)
#define OFF_ICN (OFF_XF + SZ_XF)
#define OFF_IRN (OFF_ICN + (size_t)BB*FLEN)
#define OFF_XE  (OFF_IRN + (size_t)BB*NN)   // after k_x1, reused as x1 hi/lo fp16
#define SZ_BNH  ((size_t)BB*NN*HH)
#define OFF_X1  (OFF_XE + SZ_BNH)           // fp32 x1; dead after k_adp -> reused as cand list
#define OFF_ADP (OFF_X1 + SZ_BNH)           // adp hi/lo fp16
#define OFF_CSW (OFF_ADP + SZ_BNH)
#define OFF_LNS (OFF_CSW + HH)
#define OFF_LNF (OFF_LNS + 16)
// xf region reuse (after k_xe): rowmax[16000]u32 @ +0, cnt[16000]u32 @ +16000,
// pcnt[16000]u32 @ +32000, pdef[16000]f32 @ +48000, plist[16000*20]uint2 @ +64000

__device__ __forceinline__ float wredSum(float v) {
#pragma unroll
  for (int o = 32; o > 0; o >>= 1) v += __shfl_down(v, o, 64);
  return v;
}

// fp16 hi/lo split: v = hi + lo + O(2^-22 * v)
__device__ __forceinline__ void split16(float v, ushort_t& hi, ushort_t& lo) {
  _Float16 h = (_Float16)v;
  _Float16 l = (_Float16)(v - (float)h);
  union { _Float16 f; ushort_t u; } a, b;
  a.f = h; b.f = l;
  hi = a.u; lo = b.u;
}

__global__ void k_init(const float* __restrict__ Wx, float* __restrict__ csw,
                       float* __restrict__ lns) {
  int k = threadIdx.x;
  float s = 0.f;
  for (int h = 0; h < HH; ++h) s += Wx[h * HH + k];
  csw[k] = s;
  if (k < 16) lns[k] = 0.f;
}

__global__ void k_tw(float* __restrict__ tw) {
  int id = blockIdx.x * 256 + threadIdx.x;
  if (id >= TT * FLEN) return;
  int t = id / FLEN, f = id % FLEN;
  int r = (t * f) % TT;
  double th = -2.0 * 3.14159265358979323846 * (double)r / (double)TT;
  tw[2 * id]     = (float)cos(th);
  tw[2 * id + 1] = (float)sin(th);
}

__global__ void k_dft(const float* __restrict__ x, const float* __restrict__ tw,
                      float* __restrict__ xf) {
  __shared__ __align__(16) float Xs[16][128];
  __shared__ __align__(16) float TWs[16][32][2];
  const int b = blockIdx.z;
  const int f0 = blockIdx.y * 32;
  const int n0 = blockIdx.x * 128;
  const int tid = threadIdx.x;
  const int tn = tid & 31;
  const int tf = tid >> 5;
  float ar[4][4] = {}, ai[4][4] = {};
  for (int t0 = 0; t0 < TT; t0 += 16) {
    __syncthreads();
    for (int l = tid; l < 512; l += 256) {
      int row = l >> 5, q = l & 31;
      int n = n0 + q * 4;
      const float* src = x + ((size_t)b * TT + (t0 + row)) * NN + n;
      float4 v = make_float4(0, 0, 0, 0);
      if (n + 3 < NN) v = *(const float4*)src;
      else {
        if (n + 0 < NN) v.x = src[0];
        if (n + 1 < NN) v.y = src[1];
        if (n + 2 < NN) v.z = src[2];
        if (n + 3 < NN) v.w = src[3];
      }
      *(float4*)&Xs[row][q * 4] = v;
    }
    for (int l = tid; l < 512; l += 256) {
      int row = l >> 5, ff = l & 31;
      int f = f0 + ff;
      float2 cs = make_float2(0, 0);
      if (f < FLEN) cs = *(const float2*)&tw[((size_t)(t0 + row) * FLEN + f) * 2];
      *(float2*)&TWs[row][ff][0] = cs;
    }
    __syncthreads();
#pragma unroll 4
    for (int t = 0; t < 16; ++t) {
      float4 xv = *(float4*)&Xs[t][tn * 4];
      float xx[4] = {xv.x, xv.y, xv.z, xv.w};
      float4 p0 = *(float4*)&TWs[t][tf * 4][0];
      float4 p1 = *(float4*)&TWs[t][tf * 4 + 2][0];
      float c[4] = {p0.x, p0.z, p1.x, p1.z};
      float s[4] = {p0.y, p0.w, p1.y, p1.w};
#pragma unroll
      for (int i = 0; i < 4; ++i)
#pragma unroll
        for (int j = 0; j < 4; ++j) {
          ar[i][j] = fmaf(xx[j], c[i], ar[i][j]);
          ai[i][j] = fmaf(xx[j], s[i], ai[i][j]);
        }
    }
  }
#pragma unroll
  for (int i = 0; i < 4; ++i) {
    int f = f0 + tf * 4 + i;
    if (f >= FLEN) continue;
    float* dst = &xf[((size_t)b * FLEN + f) * NN];
    float o[4];
#pragma unroll
    for (int j = 0; j < 4; ++j)
      o[j] = sqrtf(ar[i][j] * ar[i][j] + ai[i][j] * ai[i][j]);
    int n = n0 + tn * 4;
    if (n + 3 < NN) *(float4*)&dst[n] = make_float4(o[0], o[1], o[2], o[3]);
    else {
#pragma unroll
      for (int j = 0; j < 4; ++j) if (n + j < NN) dst[n + j] = o[j];
    }
  }
}

__global__ void k_colnorm(const float* __restrict__ xf, float* __restrict__ icn) {
  __shared__ float sc[4];
  int bf = blockIdx.x;
  const float* rowp = xf + (size_t)bf * NN;
  float s = 0.f;
  for (int i = threadIdx.x; i < NN; i += 256) { float v = rowp[i]; s = fmaf(v, v, s); }
  s = wredSum(s);
  int lane = threadIdx.x & 63, w = threadIdx.x >> 6;
  if (lane == 0) sc[w] = s;
  __syncthreads();
  if (threadIdx.x == 0)
    icn[bf] = 1.f / fmaxf(sqrtf(sc[0] + sc[1] + sc[2] + sc[3]), 1e-12f);
}

__global__ void k_rownorm(const float* __restrict__ xf, const float* __restrict__ icn,
                          float* __restrict__ irn) {
  int b = blockIdx.y;
  int n = blockIdx.x * 256 + threadIdx.x;
  if (n >= NN) return;
  float s = 0.f;
  for (int f = 0; f < FLEN; ++f) {
    float v = xf[((size_t)b * FLEN + f) * NN + n] * icn[b * FLEN + f];
    s = fmaf(v, v, s);
  }
  irn[b * NN + n] = 1.f / fmaxf(sqrtf(s), 1e-12f);
}

__global__ void k_xe(const float* __restrict__ xf, const float* __restrict__ icn,
                     const float* __restrict__ irn, const float* __restrict__ Ex,
                     float* __restrict__ xe) {
  __shared__ __align__(16) float As[16][64];
  __shared__ __align__(16) float Bs[16][128];
  const int b = blockIdx.y;
  const int n0 = blockIdx.x * 64;
  const int tid = threadIdx.x;
  const int tn = tid >> 4, te = tid & 15;
  float acc[4][8] = {};
  for (int f0 = 0; f0 < 160; f0 += 16) {
    __syncthreads();
    {
      int kt = tid >> 4, q = tid & 15;
      int f = f0 + kt;
      int n = n0 + q * 4;
      float4 v = make_float4(0, 0, 0, 0);
      if (f < FLEN) {
        float ic = icn[b * FLEN + f];
        const float* src = &xf[((size_t)b * FLEN + f) * NN + n];
        if (n + 3 < NN) v = *(const float4*)src;
        else {
          if (n + 0 < NN) v.x = src[0];
          if (n + 1 < NN) v.y = src[1];
          if (n + 2 < NN) v.z = src[2];
          if (n + 3 < NN) v.w = src[3];
        }
        v.x *= ic; v.y *= ic; v.z *= ic; v.w *= ic;
      }
      *(float4*)&As[kt][q * 4] = v;
    }
    for (int l = tid; l < 512; l += 256) {
      int kt = l >> 5, q = l & 31;
      int f = f0 + kt;
      float4 v = make_float4(0, 0, 0, 0);
      if (f < FLEN) v = *(const float4*)&Ex[(size_t)f * EE + q * 4];
      *(float4*)&Bs[kt][q * 4] = v;
    }
    __syncthreads();
#pragma unroll
    for (int k = 0; k < 16; ++k) {
      float4 a  = *(float4*)&As[k][tn * 4];
      float4 b0 = *(float4*)&Bs[k][te * 4];
      float4 b1 = *(float4*)&Bs[k][64 + te * 4];
      float av[4] = {a.x, a.y, a.z, a.w};
      float bv[8] = {b0.x, b0.y, b0.z, b0.w, b1.x, b1.y, b1.z, b1.w};
#pragma unroll
      for (int i = 0; i < 4; ++i)
#pragma unroll
        for (int j = 0; j < 8; ++j)
          acc[i][j] = fmaf(av[i], bv[j], acc[i][j]);
    }
  }
#pragma unroll
  for (int i = 0; i < 4; ++i) {
    int n = n0 + tn * 4 + i;
    if (n >= NN) continue;
    float sc = irn[b * NN + n];
    float* dst = &xe[((size_t)b * NN + n) * EE];
    *(float4*)&dst[te * 4] =
        make_float4(acc[i][0] * sc, acc[i][1] * sc, acc[i][2] * sc, acc[i][3] * sc);
    *(float4*)&dst[64 + te * 4] =
        make_float4(acc[i][4] * sc, acc[i][5] * sc, acc[i][6] * sc, acc[i][7] * sc);
  }
}

__global__ void k_x1(const float* xe, const float* __restrict__ nodes,
                     const float* __restrict__ Wd, float* __restrict__ x1,
                     ushort_t* x1hl) {
  __shared__ __align__(16) float xk[8][DKK];
  __shared__ float red[4][32][33];
  const int n = blockIdx.x;
  const int tid = threadIdx.x;
  {
    int b = tid >> 5, q = tid & 31;
    *(float4*)&xk[b][q * 4] = *(const float4*)&xe[((size_t)b * NN + n) * EE + q * 4];
  }
  if (tid < 128) {
    int b = tid >> 4, i = tid & 15;
    xk[b][EE + i] = nodes[(size_t)n * IDD + i];
  }
  __syncthreads();
  const int h4 = tid & 31;
  const int dg = tid >> 5;
  float acc[8][4] = {};
  for (int d = dg; d < DKK; d += 8) {
    float4 wv = *(const float4*)&Wd[((size_t)n * DKK + d) * HH + h4 * 4];
#pragma unroll
    for (int b = 0; b < 8; ++b) {
      float xv = xk[b][d];
      acc[b][0] = fmaf(xv, wv.x, acc[b][0]);
      acc[b][1] = fmaf(xv, wv.y, acc[b][1]);
      acc[b][2] = fmaf(xv, wv.z, acc[b][2]);
      acc[b][3] = fmaf(xv, wv.w, acc[b][3]);
    }
  }
#pragma unroll
  for (int b = 0; b < 8; ++b)
#pragma unroll
    for (int j = 0; j < 4; ++j)
      acc[b][j] += __shfl_xor(acc[b][j], 32, 64);
  const int wv_ = tid >> 6, lane = tid & 63;
  if (lane < 32) {
#pragma unroll
    for (int b = 0; b < 8; ++b)
#pragma unroll
      for (int j = 0; j < 4; ++j)
        red[wv_][lane][b * 4 + j] = acc[b][j];
  }
  __syncthreads();
#pragma unroll
  for (int o = 0; o < 4; ++o) {
    int idx = tid + o * 256;
    int b = idx >> 7, h = idx & 127;
    float s = red[0][h >> 2][b * 4 + (h & 3)] + red[1][h >> 2][b * 4 + (h & 3)] +
              red[2][h >> 2][b * 4 + (h & 3)] + red[3][h >> 2][b * 4 + (h & 3)];
    s = fmaxf(s, 0.f);
    x1[((size_t)b * NN + n) * HH + h] = s;
    ushort_t hi, lo;
    split16(s, hi, lo);
    size_t base = ((size_t)b * NN + n) * 256;
    x1hl[base + h] = hi;
    x1hl[base + 128 + h] = lo;
  }
}

__global__ void k_ln_stats(const float* __restrict__ x1, float* __restrict__ lns) {
  __shared__ float sc[4], sc2[4];
  int b = blockIdx.y, chunk = blockIdx.x;
  const float* base = x1 + (size_t)b * NN * HH + (size_t)chunk * 8000;
  float s = 0.f, s2 = 0.f;
  for (int i = threadIdx.x; i < 8000; i += 256) {
    float v = base[i];
    s += v; s2 = fmaf(v, v, s2);
  }
  s = wredSum(s); s2 = wredSum(s2);
  int lane = threadIdx.x & 63, w = threadIdx.x >> 6;
  if (lane == 0) { sc[w] = s; sc2[w] = s2; }
  __syncthreads();
  if (threadIdx.x == 0) {
    atomicAdd(&lns[b], sc[0] + sc[1] + sc[2] + sc[3]);
    atomicAdd(&lns[8 + b], sc2[0] + sc2[1] + sc2[2] + sc2[3]);
  }
}

__global__ void k_ln_final(const float* __restrict__ lns, float* __restrict__ lnf) {
  int b = threadIdx.x;
  if (b < 8) {
    float cnt = (float)(NN * HH);
    float mu = lns[b] / cnt;
    float var = fmaxf(lns[8 + b] / cnt - mu * mu, 0.f);
    lnf[b] = mu;
    lnf[8 + b] = 1.f / sqrtf(var + 1e-8f);
  }
}

__global__ void k_adp(const float* __restrict__ x1, const float* __restrict__ Wx,
                      const float* __restrict__ csw, const float* __restrict__ lnf,
                      ushort_t* __restrict__ adphl) {
  __shared__ __align__(16) float As[16][64];
  __shared__ __align__(16) float Bs[16][128];
  const int r0 = blockIdx.x * 64;
  const int tid = threadIdx.x;
  const int tn = tid >> 4, te = tid & 15;
  float acc[4][8] = {};
  for (int k0 = 0; k0 < HH; k0 += 16) {
    __syncthreads();
    {
      int rr = tid >> 2, kq = tid & 3;
      float4 v = *(const float4*)&x1[(size_t)(r0 + rr) * HH + k0 + kq * 4];
      As[kq * 4 + 0][rr] = v.x;
      As[kq * 4 + 1][rr] = v.y;
      As[kq * 4 + 2][rr] = v.z;
      As[kq * 4 + 3][rr] = v.w;
    }
    for (int l = tid; l < 512; l += 256) {
      int kt = l >> 5, q = l & 31;
      *(float4*)&Bs[kt][q * 4] = *(const float4*)&Wx[(size_t)(k0 + kt) * HH + q * 4];
    }
    __syncthreads();
#pragma unroll
    for (int k = 0; k < 16; ++k) {
      float4 a  = *(float4*)&As[k][tn * 4];
      float4 b0 = *(float4*)&Bs[k][te * 4];
      float4 b1 = *(float4*)&Bs[k][64 + te * 4];
      float av[4] = {a.x, a.y, a.z, a.w};
      float bv[8] = {b0.x, b0.y, b0.z, b0.w, b1.x, b1.y, b1.z, b1.w};
#pragma unroll
      for (int i = 0; i < 4; ++i)
#pragma unroll
        for (int j = 0; j < 8; ++j)
          acc[i][j] = fmaf(av[i], bv[j], acc[i][j]);
    }
  }
  float4 c0 = *(const float4*)&csw[te * 4];
  float4 c1 = *(const float4*)&csw[64 + te * 4];
  float cw[8] = {c0.x, c0.y, c0.z, c0.w, c1.x, c1.y, c1.z, c1.w};
#pragma unroll
  for (int i = 0; i < 4; ++i) {
    int r = r0 + tn * 4 + i;
    int b = r / NN;
    float mu = lnf[b], isd = lnf[8 + b];
    size_t base = (size_t)r * 256;
    ushort_t hi[8], lo[8];
#pragma unroll
    for (int j = 0; j < 8; ++j) {
      float o = (acc[i][j] - mu * cw[j]) * isd;
      split16(o, hi[j], lo[j]);
    }
    ushort4 u;
    u.x = hi[0]; u.y = hi[1]; u.z = hi[2]; u.w = hi[3];
    *(ushort4*)&adphl[base + te * 4] = u;
    u.x = hi[4]; u.y = hi[5]; u.z = hi[6]; u.w = hi[7];
    *(ushort4*)&adphl[base + 64 + te * 4] = u;
    u.x = lo[0]; u.y = lo[1]; u.z = lo[2]; u.w = lo[3];
    *(ushort4*)&adphl[base + 128 + te * 4] = u;
    u.x = lo[4]; u.y = lo[5]; u.z = lo[6]; u.w = lo[7];
    *(ushort4*)&adphl[base + 128 + 64 + te * 4] = u;
  }
}

// ---- shared MFMA tile compute for the two adj passes ----
#define ADJ_PROLOG \
  __shared__ __align__(16) ushort_t lds[4][128 * 32]; \
  const int b = blockIdx.z; \
  const int n0 = blockIdx.y * 128; \
  const int m0 = blockIdx.x * 128; \
  const int tid = threadIdx.x; \
  const int w = tid >> 6; \
  const int lane = tid & 63; \
  const int quad = lane >> 4, r16 = lane & 15; \
  const int rBase = (w >> 1) * 64; \
  const int cBase = (w & 1) * 64; \
  f32x4 acc[4][4]; \
  _Pragma("unroll") for (int i = 0; i < 4; ++i) \
  _Pragma("unroll") for (int j = 0; j < 4; ++j) acc[i][j] = (f32x4){0.f,0.f,0.f,0.f}; \
  const ushort_t* src = (w < 2) ? adphl : x1hl; \
  const int rg0 = (w < 2) ? n0 : m0; \
  const int loOff = (w & 1) ? 128 : 0; \
  for (int k0 = 0; k0 < HH; k0 += 32) { \
    __syncthreads(); \
    _Pragma("unroll") for (int i = 0; i < 8; ++i) { \
      int cl = i * 64 + lane; \
      int row = cl >> 2, c = cl & 3; \
      int gr = rg0 + row; if (gr > NN - 1) gr = NN - 1; \
      const uint4* gp = (const uint4*)(src + ((size_t)(b * NN + gr)) * 256 + loOff + k0 + c * 8); \
      uint4 v = *gp; \
      *(uint4*)&lds[w][row * 32 + ((c ^ (row & 3)) * 8)] = v; \
    } \
    __syncthreads(); \
    half8 Ah[4], Al[4], Bh[4], Bl[4]; \
    _Pragma("unroll") for (int i = 0; i < 4; ++i) { \
      int ar = rBase + i * 16 + r16; \
      int aoff = ar * 32 + ((quad ^ (ar & 3)) * 8); \
      Ah[i] = *(half8*)&lds[0][aoff]; \
      Al[i] = *(half8*)&lds[1][aoff]; \
      int br = cBase + i * 16 + r16; \
      int boff = br * 32 + ((quad ^ (br & 3)) * 8); \
      Bh[i] = *(half8*)&lds[2][boff]; \
      Bl[i] = *(half8*)&lds[3][boff]; \
    } \
    _Pragma("unroll") for (int i = 0; i < 4; ++i) \
    _Pragma("unroll") for (int j = 0; j < 4; ++j) { \
      acc[i][j] = __builtin_amdgcn_mfma_f32_16x16x32_f16(Ah[i], Bh[j], acc[i][j], 0, 0, 0); \
      acc[i][j] = __builtin_amdgcn_mfma_f32_16x16x32_f16(Ah[i], Bl[j], acc[i][j], 0, 0, 0); \
      acc[i][j] = __builtin_amdgcn_mfma_f32_16x16x32_f16(Al[i], Bh[j], acc[i][j], 0, 0, 0); \
    } \
  }

// pass 1: per-row max -> atomicMax(rowmax)
__global__ void k_adj_max(const ushort_t* __restrict__ adphl,
                          const ushort_t* __restrict__ x1hl,
                          unsigned* __restrict__ rowmax) {
  ADJ_PROLOG
#pragma unroll
  for (int i = 0; i < 4; ++i) {
    float mx[4];
#pragma unroll
    for (int reg = 0; reg < 4; ++reg) {
      float m_ = acc[i][0][reg];
      m_ = fmaxf(m_, acc[i][1][reg]);
      m_ = fmaxf(m_, acc[i][2][reg]);
      m_ = fmaxf(m_, acc[i][3][reg]);
#pragma unroll
      for (int o = 1; o < 16; o <<= 1) m_ = fmaxf(m_, __shfl_xor(m_, o, 64));
      mx[reg] = fmaxf(m_, 0.f);
    }
    if (r16 == 0) {
#pragma unroll
      for (int reg = 0; reg < 4; ++reg) {
        int n = n0 + rBase + i * 16 + quad * 4 + reg;
        if (n < NN) atomicMax(&rowmax[b * NN + n], __float_as_uint(mx[reg]));
      }
    }
  }
}

// pass 2: recompute; append candidates (v > rowmax - 87)
__global__ void k_cand(const ushort_t* __restrict__ adphl,
                       const ushort_t* __restrict__ x1hl,
                       const unsigned* __restrict__ rowmax,
                       unsigned* __restrict__ cnt, uint2* __restrict__ cand) {
  ADJ_PROLOG
#pragma unroll
  for (int i = 0; i < 4; ++i) {
#pragma unroll
    for (int reg = 0; reg < 4; ++reg) {
      int n = n0 + rBase + i * 16 + quad * 4 + reg;
      if (n >= NN) continue;
      int rr = b * NN + n;
      float thr = __uint_as_float(rowmax[rr]) - 87.0f;
#pragma unroll
      for (int j = 0; j < 4; ++j) {
        float v = fmaxf(acc[i][j][reg], 0.f);
        int m = m0 + cBase + j * 16 + r16;
        if (m < NN && v > thr) {
          unsigned slot = atomicAdd(&cnt[rr], 1u);
          if (slot < 64u) cand[(size_t)rr * 64 + slot] = make_uint2((unsigned)m, __float_as_uint(v));
        }
      }
    }
  }
}

// one wave per row: exact top-min(20,cnt) among candidates, softmax params
__global__ void k_select(const unsigned* __restrict__ rowmax,
                         const unsigned* __restrict__ cnt,
                         const uint2* __restrict__ cand,
                         unsigned* __restrict__ pcnt, float* __restrict__ pdef,
                         uint2* __restrict__ plist) {
  const int r = blockIdx.x;
  const int lane = threadIdx.x;
  unsigned cn = cnt[r]; if (cn > 64u) cn = 64u;
  float m = __uint_as_float(rowmax[r]);
  float val = -1.f; int idx = 0x7fffffff;
  if (lane < (int)cn) {
    uint2 c = cand[(size_t)r * 64 + lane];
    idx = (int)c.x; val = __uint_as_float(c.y);
  }
  float em = expf(-m);
  float Dacc = 0.f; int Kp = 0;
  float myV = 0.f; int myI = -1;
  for (int it = 0; it < KTOP; ++it) {
    float wv = val; int wi = idx;
#pragma unroll
    for (int o = 32; o > 0; o >>= 1) {
      float ov = __shfl_xor(wv, o, 64);
      int oi = __shfl_xor(wi, o, 64);
      if (ov > wv || (ov == wv && oi < wi)) { wv = ov; wi = oi; }
    }
    if (wv < 0.f) break;
    Kp++;
    Dacc += expf(wv - m);
    if (val == wv && idx == wi) val = -2.f;
    if (lane == it) { myV = wv; myI = wi; }
  }
  float D = Dacc + ((float)NN - (float)Kp) * em;
  float invD = 1.f / D;
  if (lane == 0) { pdef[r] = em * invD; pcnt[r] = (unsigned)Kp; }
  if (lane < Kp) plist[(size_t)r * KTOP + lane] =
      make_uint2((unsigned)myI, __float_as_uint(expf(myV - m) * invD));
}

// fill defaults + patch top-k, one block per row
__global__ void k_fill(const unsigned* __restrict__ pcnt, const float* __restrict__ pdef,
                       const uint2* __restrict__ plist, float* __restrict__ out) {
  const int r = blockIdx.x;
  const int tid = threadIdx.x;
  float dv = pdef[r];
  float4 q = make_float4(dv, dv, dv, dv);
  float* g = out + (size_t)r * NN;
  for (int c = tid; c < 500; c += 256) ((float4*)g)[c] = q;
  __syncthreads();
  if (tid < (int)pcnt[r]) {
    uint2 p = plist[(size_t)r * KTOP + tid];
    g[p.x] = __uint_as_float(p.y);
  }
}

extern "C" void kernel_launch(void* const* d_in, const int* in_sizes, int n_in,
                              void* d_out, int out_size, void* d_ws, size_t ws_size,
                              hipStream_t stream) {
  const float* x     = (const float*)d_in[0];
  const float* Ex    = (const float*)d_in[1];
  const float* nodes = (const float*)d_in[2];
  const float* Wd    = (const float*)d_in[3];
  const float* Wx    = (const float*)d_in[4];
  float* out = (float*)d_out;
  float* w = (float*)d_ws;
  float* tw  = w + OFF_TW;
  float* xf  = w + OFF_XF;
  float* icn = w + OFF_ICN;
  float* irn = w + OFF_IRN;
  float* xe  = w + OFF_XE;
  float* x1  = w + OFF_X1;
  float* csw = w + OFF_CSW;
  float* lns = w + OFF_LNS;
  float* lnf = w + OFF_LNF;
  ushort_t* adphl = (ushort_t*)(w + OFF_ADP);
  ushort_t* x1hl  = (ushort_t*)(w + OFF_XE);
  // xf region reuse (dead after k_xe):
  unsigned* rowmax = (unsigned*)(w + OFF_XF);
  unsigned* cnt    = (unsigned*)(w + OFF_XF) + 16000;
  unsigned* pcnt   = (unsigned*)(w + OFF_XF) + 32000;
  float*    pdef   = (float*)(w + OFF_XF) + 48000;
  uint2*    plist  = (uint2*)((w + OFF_XF) + 64000);
  // x1 fp32 region reuse (dead after k_adp): 16000*64 uint2 = SZ_BNH floats
  uint2*    cand   = (uint2*)(w + OFF_X1);

  k_init<<<1, 128, 0, stream>>>(Wx, csw, lns);
  k_tw<<<(TT * FLEN + 255) / 256, 256, 0, stream>>>(tw);
  k_dft<<<dim3(16, 5, BB), 256, 0, stream>>>(x, tw, xf);
  k_colnorm<<<BB * FLEN, 256, 0, stream>>>(xf, icn);
  k_rownorm<<<dim3(8, BB), 256, 0, stream>>>(xf, icn, irn);
  k_xe<<<dim3(32, BB), 256, 0, stream>>>(xf, icn, irn, Ex, xe);
  // rowmax+cnt zero-init (xf now dead; stream-ordered after k_xe)
  hipMemsetAsync(rowmax, 0, 32000 * sizeof(unsigned), stream);
  k_x1<<<NN, 256, 0, stream>>>(xe, nodes, Wd, x1, x1hl);
  k_ln_stats<<<dim3(32, BB), 256, 0, stream>>>(x1, lns);
  k_ln_final<<<1, 64, 0, stream>>>(lns, lnf);
  k_adp<<<250, 256, 0, stream>>>(x1, Wx, csw, lnf, adphl);
  k_adj_max<<<dim3(16, 16, BB), 256, 0, stream>>>(adphl, x1hl, rowmax);
  k_cand<<<dim3(16, 16, BB), 256, 0, stream>>>(adphl, x1hl, rowmax, cnt, cand);
  k_select<<<BB * NN, 64, 0, stream>>>(rowmax, cnt, cand, pcnt, pdef, plist);
  k_fill<<<BB * NN, 256, 0, stream>>>(pcnt, pdef, plist, out);
}